// Round 1
// baseline (662.160 us; speedup 1.0000x reference)
//
#include <hip/hip_runtime.h>
#include <hip/hip_bf16.h>
#include <stdint.h>

// BitLinear: out[m][n] = scale[n] * sum_k x[m][k] * q[n][k], q ternary.
// M = B*S = 8192, K = 2048, N = 8192.

typedef float floatx4 __attribute__((ext_vector_type(4)));
typedef __bf16 bf16x8 __attribute__((ext_vector_type(8)));

#define BM 128
#define BN 128
#define BK 32

// ---------------- Kernel 1: per-row scale + ternary quantize to bf16 --------
__global__ __launch_bounds__(256) void quant_weight(
    const float* __restrict__ W, uint16_t* __restrict__ Q,
    float* __restrict__ scale, int K /*2048*/)
{
    const int o = blockIdx.x;
    const int t = threadIdx.x;
    const float* row = W + (size_t)o * K;
    const float4* row4 = (const float4*)row;

    float4 v0 = row4[t];          // floats [4t, 4t+3]
    float4 v1 = row4[t + 256];    // floats [1024+4t, ...]
    float s = fabsf(v0.x) + fabsf(v0.y) + fabsf(v0.z) + fabsf(v0.w)
            + fabsf(v1.x) + fabsf(v1.y) + fabsf(v1.z) + fabsf(v1.w);
    // wave64 reduce
    #pragma unroll
    for (int off = 32; off; off >>= 1) s += __shfl_down(s, off, 64);

    __shared__ float partial[4];
    __shared__ float inv_sh;
    if ((t & 63) == 0) partial[t >> 6] = s;
    __syncthreads();
    if (t == 0) {
        float tot = partial[0] + partial[1] + partial[2] + partial[3];
        float sc = fmaxf(tot / (float)K, 1e-5f);
        scale[o] = sc;
        inv_sh = 1.0f / sc;
    }
    __syncthreads();
    const float inv = inv_sh;

    uint16_t* qrow = Q + (size_t)o * K;
    float q0[4] = {v0.x, v0.y, v0.z, v0.w};
    float q1[4] = {v1.x, v1.y, v1.z, v1.w};
    ushort4 o0, o1;
    unsigned short* p0 = (unsigned short*)&o0;
    unsigned short* p1 = (unsigned short*)&o1;
    #pragma unroll
    for (int i = 0; i < 4; ++i) {
        float a = fminf(fmaxf(rintf(q0[i] * inv), -1.f), 1.f);  // {-1,0,1}
        float b = fminf(fmaxf(rintf(q1[i] * inv), -1.f), 1.f);
        p0[i] = (unsigned short)(__float_as_uint(a) >> 16);     // exact in bf16
        p1[i] = (unsigned short)(__float_as_uint(b) >> 16);
    }
    ((ushort4*)qrow)[t] = o0;
    ((ushort4*)qrow)[t + 256] = o1;
}

// ---------------- Kernel 2: x fp32 -> bf16 (RNE) ----------------------------
__global__ __launch_bounds__(256) void cvt_bf16(
    const float* __restrict__ X, uint16_t* __restrict__ Y)
{
    const size_t i = (size_t)blockIdx.x * blockDim.x + threadIdx.x; // 8 elems each
    const float4* x4 = (const float4*)X;
    float4 a = x4[2 * i];
    float4 b = x4[2 * i + 1];
    float v[8] = {a.x, a.y, a.z, a.w, b.x, b.y, b.z, b.w};
    ushort4 lo, hi;
    unsigned short* pl = (unsigned short*)&lo;
    unsigned short* ph = (unsigned short*)&hi;
    #pragma unroll
    for (int j = 0; j < 4; ++j) {
        unsigned ua = __float_as_uint(v[j]);
        unsigned ub = __float_as_uint(v[j + 4]);
        pl[j] = (unsigned short)((ua + 0x7fffu + ((ua >> 16) & 1u)) >> 16);
        ph[j] = (unsigned short)((ub + 0x7fffu + ((ub >> 16) & 1u)) >> 16);
    }
    ((ushort4*)Y)[2 * i] = lo;
    ((ushort4*)Y)[2 * i + 1] = hi;
}

// ---------------- Kernel 3: bf16 GEMM C = A * B^T, scaled epilogue ----------
__device__ inline void gload_lds16(const void* g, void* l) {
    __builtin_amdgcn_global_load_lds(
        (const __attribute__((address_space(1))) void*)g,
        (__attribute__((address_space(3))) void*)l, 16, 0, 0);
}

__global__ __launch_bounds__(256) void gemm_bt_scaled(
    const uint16_t* __restrict__ A,   // [M,K] bf16 bits
    const uint16_t* __restrict__ B,   // [N,K] bf16 bits (ternary)
    const float* __restrict__ scale,  // [N]
    float* __restrict__ C,            // [M,N]
    int M, int N, int K)
{
    __shared__ __align__(16) uint16_t sA[BM * BK]; // 8 KiB
    __shared__ __align__(16) uint16_t sB[BN * BK]; // 8 KiB

    const int tid  = threadIdx.x;
    const int lane = tid & 63;
    const int wv   = tid >> 6;
    const int wm   = wv & 1;     // wave row in 2x2
    const int wn   = wv >> 1;    // wave col in 2x2
    const int bm   = blockIdx.y;
    const int bn   = blockIdx.x;
    const int rowA0 = bm * BM;
    const int rowB0 = bn * BN;

    const int lrow  = lane & 15;   // MFMA m / n index
    const int kquad = lane >> 4;   // 0..3 -> k-chunk
    const int aoff0 = (wm * 64 + lrow) * BK + kquad * 8;
    const int boff0 = (wn * 64 + lrow) * BK + kquad * 8;

    floatx4 acc[4][4] = {};

    for (int kk = 0; kk < K; kk += BK) {
        // stage A: 512 chunks of 16B, 2 per thread; LDS dest = base + lane*16
        #pragma unroll
        for (int j = 0; j < 2; ++j) {
            int c = tid + 256 * j;
            const uint16_t* ga = A + (size_t)(rowA0 + (c >> 2)) * K + kk + (c & 3) * 8;
            gload_lds16(ga, &sA[c * 8]);
        }
        #pragma unroll
        for (int j = 0; j < 2; ++j) {
            int c = tid + 256 * j;
            const uint16_t* gb = B + (size_t)(rowB0 + (c >> 2)) * K + kk + (c & 3) * 8;
            gload_lds16(gb, &sB[c * 8]);
        }
        __syncthreads();

        bf16x8 af[4], bfr[4];
        #pragma unroll
        for (int mt = 0; mt < 4; ++mt)
            af[mt] = *(const bf16x8*)&sA[aoff0 + mt * 16 * BK];
        #pragma unroll
        for (int nt = 0; nt < 4; ++nt)
            bfr[nt] = *(const bf16x8*)&sB[boff0 + nt * 16 * BK];

        #pragma unroll
        for (int mt = 0; mt < 4; ++mt)
            #pragma unroll
            for (int nt = 0; nt < 4; ++nt)
                acc[mt][nt] = __builtin_amdgcn_mfma_f32_16x16x32_bf16(
                    af[mt], bfr[nt], acc[mt][nt], 0, 0, 0);
        __syncthreads();
    }

    // epilogue: D mapping col = lane&15 (n), row = (lane>>4)*4 + reg (m)
    const int colb = rowB0 + wn * 64 + lrow;
    const int rowb = rowA0 + wm * 64 + kquad * 4;
    #pragma unroll
    for (int nt = 0; nt < 4; ++nt) {
        const float sc = scale[colb + nt * 16];
        #pragma unroll
        for (int mt = 0; mt < 4; ++mt) {
            #pragma unroll
            for (int r = 0; r < 4; ++r) {
                C[(size_t)(rowb + mt * 16 + r) * N + colb + nt * 16] =
                    acc[mt][nt][r] * sc;
            }
        }
    }
}

extern "C" void kernel_launch(void* const* d_in, const int* in_sizes, int n_in,
                              void* d_out, int out_size, void* d_ws, size_t ws_size,
                              hipStream_t stream) {
    const float* x = (const float*)d_in[0];      // [4,2048,2048] fp32
    const float* w = (const float*)d_in[1];      // [8192,2048] fp32
    float* out = (float*)d_out;                  // [4,2048,8192] fp32

    const int M = 8192, K = 2048, N = 8192;

    char* ws = (char*)d_ws;
    float*    scale = (float*)ws;                            // 32 KiB
    uint16_t* Xb    = (uint16_t*)(ws + 32768);               // 32 MiB
    uint16_t* Qb    = (uint16_t*)(ws + 32768 + (size_t)M * K * 2); // 32 MiB

    quant_weight<<<N, 256, 0, stream>>>(w, Qb, scale, K);
    cvt_bf16<<<(M * K / 8) / 256, 256, 0, stream>>>(x, Xb);
    gemm_bt_scaled<<<dim3(N / BN, M / BM), 256, 0, stream>>>(Xb, Qb, scale, out, M, N, K);
}

// Round 2
// 655.088 us; speedup vs baseline: 1.0108x; 1.0108x over previous
//
#include <hip/hip_runtime.h>
#include <hip/hip_bf16.h>
#include <stdint.h>

// BitLinear: out[m][n] = scale[n] * sum_k x[m][k] * q[n][k], q ternary.
// M = B*S = 8192, K = 2048, N = 8192.
// fp16 MFMA path: q exact in fp16, x rounded to fp16 (rel err 2^-11).

typedef float  floatx4 __attribute__((ext_vector_type(4)));
typedef _Float16 f16x8 __attribute__((ext_vector_type(8)));
typedef _Float16 f16x4 __attribute__((ext_vector_type(4)));

#define BM 128
#define BN 128
#define BK 32

// ---------------- Kernel 1: per-row scale + ternary quantize to fp16 --------
// One wave per row, 4 waves (4 rows) per 256-thread block. No barriers.
__global__ __launch_bounds__(256) void quant_weight(
    const float* __restrict__ W, f16x4* __restrict__ Q,
    float* __restrict__ scale, int K /*2048*/)
{
    const int wave = threadIdx.x >> 6;
    const int lane = threadIdx.x & 63;
    const int row  = blockIdx.x * 4 + wave;

    const float4* row4 = (const float4*)(W + (size_t)row * K);  // 512 float4
    float4 v[8];
    float s = 0.f;
    #pragma unroll
    for (int i = 0; i < 8; ++i) {
        v[i] = row4[lane + 64 * i];
        s += fabsf(v[i].x) + fabsf(v[i].y) + fabsf(v[i].z) + fabsf(v[i].w);
    }
    // butterfly reduce — all lanes get the total
    #pragma unroll
    for (int m = 1; m < 64; m <<= 1) s += __shfl_xor(s, m, 64);

    const float sc  = fmaxf(s / (float)K, 1e-5f);
    if (lane == 0) scale[row] = sc;
    const float inv = 1.0f / sc;

    f16x4* qrow = Q + (size_t)row * (K / 4);
    #pragma unroll
    for (int i = 0; i < 8; ++i) {
        float t[4] = {v[i].x, v[i].y, v[i].z, v[i].w};
        f16x4 o;
        #pragma unroll
        for (int j = 0; j < 4; ++j)
            o[j] = (_Float16)fminf(fmaxf(rintf(t[j] * inv), -1.f), 1.f);
        qrow[lane + 64 * i] = o;
    }
}

// ---------------- Kernel 2: x fp32 -> fp16 (RNE) ----------------------------
__global__ __launch_bounds__(256) void cvt_f16(
    const float4* __restrict__ X, f16x4* __restrict__ Y)
{
    const size_t i = (size_t)blockIdx.x * blockDim.x + threadIdx.x;
    float4 a = X[i];
    f16x4 o;
    o[0] = (_Float16)a.x; o[1] = (_Float16)a.y;
    o[2] = (_Float16)a.z; o[3] = (_Float16)a.w;
    Y[i] = o;
}

// ---------------- Kernel 3: fp16 GEMM C = A * B^T, scaled epilogue ----------
__device__ inline void gload_lds16(const void* g, void* l) {
    __builtin_amdgcn_global_load_lds(
        (const __attribute__((address_space(1))) void*)g,
        (__attribute__((address_space(3))) void*)l, 16, 0, 0);
}

__global__ __launch_bounds__(256) void gemm_bt_scaled(
    const _Float16* __restrict__ A,   // [M,K]
    const _Float16* __restrict__ B,   // [N,K] ternary
    const float* __restrict__ scale,  // [N]
    float* __restrict__ C,            // [M,N]
    int M, int N, int K)
{
    // LDS tile: 512 chunks of 16B per operand. Chunk c holds global
    // (row=c>>2, kc=(c&3)^swz(row)), swz(row)=(row>>1)&3. The XOR spreads
    // fragment-read bank groups: bank_base = (row*16 + (kq^swz)*4)%32 ->
    // 8 distinct groups per 16 consecutive rows -> 2-way (free).
    __shared__ __align__(16) _Float16 sA[BM * BK]; // 8 KiB
    __shared__ __align__(16) _Float16 sB[BN * BK]; // 8 KiB

    const int tid  = threadIdx.x;
    const int lane = tid & 63;
    const int wv   = tid >> 6;
    const int wm   = wv & 1;
    const int wn   = wv >> 1;
    const int rowA0 = blockIdx.y * BM;
    const int rowB0 = blockIdx.x * BN;

    const int lrow  = lane & 15;   // MFMA m / n index
    const int kquad = lane >> 4;   // 0..3 -> k-chunk

    floatx4 acc[4][4] = {};

    // precompute fragment LDS chunk offsets (element index = chunk*8)
    int aoff[4], boff[4];
    #pragma unroll
    for (int t = 0; t < 4; ++t) {
        int ra = wm * 64 + t * 16 + lrow;
        int rb = wn * 64 + t * 16 + lrow;
        aoff[t] = (ra * 4 + (kquad ^ ((ra >> 1) & 3))) * 8;
        boff[t] = (rb * 4 + (kquad ^ ((rb >> 1) & 3))) * 8;
    }

    for (int kk = 0; kk < K; kk += BK) {
        #pragma unroll
        for (int j = 0; j < 2; ++j) {
            int c = tid + 256 * j;
            int row = c >> 2;
            int kc  = (c & 3) ^ ((row >> 1) & 3);
            gload_lds16(A + (size_t)(rowA0 + row) * K + kk + kc * 8, &sA[c * 8]);
        }
        #pragma unroll
        for (int j = 0; j < 2; ++j) {
            int c = tid + 256 * j;
            int row = c >> 2;
            int kc  = (c & 3) ^ ((row >> 1) & 3);
            gload_lds16(B + (size_t)(rowB0 + row) * K + kk + kc * 8, &sB[c * 8]);
        }
        __syncthreads();

        f16x8 af[4], bfr[4];
        #pragma unroll
        for (int mt = 0; mt < 4; ++mt) af[mt]  = *(const f16x8*)&sA[aoff[mt]];
        #pragma unroll
        for (int nt = 0; nt < 4; ++nt) bfr[nt] = *(const f16x8*)&sB[boff[nt]];

        #pragma unroll
        for (int mt = 0; mt < 4; ++mt)
            #pragma unroll
            for (int nt = 0; nt < 4; ++nt)
                acc[mt][nt] = __builtin_amdgcn_mfma_f32_16x16x32_f16(
                    af[mt], bfr[nt], acc[mt][nt], 0, 0, 0);
        __syncthreads();
    }

    // D mapping: col = lane&15 (n), row = (lane>>4)*4 + reg (m)
    const int colb = rowB0 + wn * 64 + lrow;
    const int rowb = rowA0 + wm * 64 + kquad * 4;
    #pragma unroll
    for (int nt = 0; nt < 4; ++nt) {
        const float sc = scale[colb + nt * 16];
        #pragma unroll
        for (int mt = 0; mt < 4; ++mt) {
            #pragma unroll
            for (int r = 0; r < 4; ++r) {
                C[(size_t)(rowb + mt * 16 + r) * N + colb + nt * 16] =
                    acc[mt][nt][r] * sc;
            }
        }
    }
}

extern "C" void kernel_launch(void* const* d_in, const int* in_sizes, int n_in,
                              void* d_out, int out_size, void* d_ws, size_t ws_size,
                              hipStream_t stream) {
    const float* x = (const float*)d_in[0];      // [4,2048,2048] fp32
    const float* w = (const float*)d_in[1];      // [8192,2048] fp32
    float* out = (float*)d_out;                  // [4,2048,8192] fp32

    const int M = 8192, K = 2048, N = 8192;

    char* ws = (char*)d_ws;
    float*     scale = (float*)ws;                                 // 32 KiB
    _Float16*  Xh    = (_Float16*)(ws + 32768);                    // 32 MiB
    _Float16*  Qh    = (_Float16*)(ws + 32768 + (size_t)M * K * 2);// 32 MiB

    quant_weight<<<N / 4, 256, 0, stream>>>(w, (f16x4*)Qh, scale, K);
    cvt_f16<<<(M * K / 4) / 256, 256, 0, stream>>>((const float4*)x, (f16x4*)Xh);
    gemm_bt_scaled<<<dim3(N / BN, M / BM), 256, 0, stream>>>(Xh, Qh, scale, out, M, N, K);
}